// Round 11
// baseline (55.180 us; speedup 1.0000x reference)
//
#include <hip/hip_runtime.h>
#include <hip/hip_cooperative_groups.h>

namespace cg = cooperative_groups;

namespace {

typedef unsigned short ushort_t;
typedef unsigned int uint_t;
typedef __attribute__((ext_vector_type(8))) short short8v;   // 8 bf16 (4 VGPRs)
typedef __attribute__((ext_vector_type(4))) float f32x4;     // MFMA accumulator

constexpr int kB = 8, kN = 256, kF = 128, kH = 128, kO = 64;
constexpr int kR = 8;              // real rows per block (16-row MFMA tiles, rows 8-15 garbage/discarded)
constexpr int kTPB = 1024;         // 16 waves
constexpr int kOut0 = kB * kN * kO;

// d_ws frag-slot bases (each slot = 64 lanes x 16B = 1KB, holds one B-frag)
constexpr int FW_WHH  = 0;     // w_hh : 24 tiles x 4 kf  = 96
constexpr int FW_FCW  = 96;    // fc_w :  8 tiles x 12 kf = 96
constexpr int FW_WIH  = 192;   // w_ih : 24 tiles x 4 kf  = 96
constexpr int FW_OUTW = 288;   // out_w:  4 tiles x 4 kf  = 16
constexpr int FW_GX   = 304;   // gx   :  8 b x 8 tiles x 8 kf = 512
constexpr int FW_TOTAL = 816;  // 816 KB total in d_ws

union Frag {
    uint_t  u[4];
    short8v v;
};

__device__ __forceinline__ float waveReduceAdd(float v) {
    v += __shfl_xor(v, 1);
    v += __shfl_xor(v, 2);
    v += __shfl_xor(v, 4);
    v += __shfl_xor(v, 8);
    v += __shfl_xor(v, 16);
    v += __shfl_xor(v, 32);
    return v;
}

__device__ __forceinline__ ushort_t cvt1(float f) {
    return (ushort_t)((__float_as_uint(f) + 0x8000u) >> 16);
}
__device__ __forceinline__ uint_t pk(float f0, float f1) {
    uint_t b0 = __float_as_uint(f0) + 0x8000u;
    uint_t b1 = __float_as_uint(f1) + 0x8000u;
    return (b1 & 0xFFFF0000u) | (b0 >> 16);
}
__device__ __forceinline__ float sigm(float x) {
    return __builtin_amdgcn_rcpf(1.0f + __expf(-x));
}
__device__ __forceinline__ float tanh_fast(float x) {
    x = fminf(fmaxf(x, -15.0f), 15.0f);
    float e = __expf(2.0f * x);
    return (e - 1.0f) * __builtin_amdgcn_rcpf(e + 1.0f);
}
__device__ __forceinline__ void loadWFrag(const float* __restrict__ p, Frag& b) {
    float4 lo = *(const float4*)p;
    float4 hi = *(const float4*)(p + 4);
    b.u[0] = pk(lo.x, lo.y);
    b.u[1] = pk(lo.z, lo.w);
    b.u[2] = pk(hi.x, hi.y);
    b.u[3] = pk(hi.z, hi.w);
}

#define MFMA16(A, B, C) __builtin_amdgcn_mfma_f32_16x16x32_bf16((A), (B), (C), 0, 0, 0)

// ---------------- single cooperative kernel: convert -> grid.sync -> R7 fused body ----------------
__global__ __launch_bounds__(kTPB, 4) void weak_tie_all(
    const float* __restrict__ lx, const float* __restrict__ gx,
    const float* __restrict__ mask, const int* __restrict__ key_idx,
    const float* __restrict__ hstate,
    const float* __restrict__ fc_w, const float* __restrict__ fc_b,
    const float* __restrict__ ln_g, const float* __restrict__ ln_b,
    const float* __restrict__ w_ih, const float* __restrict__ w_hh,
    const float* __restrict__ b_ih, const float* __restrict__ b_hh,
    const float* __restrict__ out_w, const float* __restrict__ out_b,
    uint4* __restrict__ ws, float* __restrict__ out)
{
    // rows 8-15 of the 16-row A-tiles are garbage; their C-rows are discarded (lane<32 guards).
    __shared__ __align__(16) ushort_t maskb[16][264];
    __shared__ __align__(16) ushort_t cmb[16][392];     // [lx | weak | key]
    __shared__ __align__(16) ushort_t hf16[16][136];
    __shared__ __align__(16) ushort_t xb16[16][136];
    __shared__ __align__(16) ushort_t hnb16[16][136];
    __shared__ __align__(16) float hf32[kR * kH];
    __shared__ __align__(16) float hb[kR * kH];
    __shared__ float denomInv[kR];

    const int tid  = threadIdx.x;
    const int b    = blockIdx.x >> 5;
    const int row0 = (blockIdx.x & 31) * kR;
    const int lane = tid & 63;
    const int wv   = tid >> 6;            // 0..15
    const int arow = lane & 15;
    const int kgrp = (lane >> 4) * 8;
    const int hi   = lane >> 4;           // 0..3 (C-rows valid only for hi<2)

    // persistent per-wave register state
    Frag  fcf[12];                                         // waves 0-7  (P1->P2)
    f32x4 gh0 = {0.f,0.f,0.f,0.f}, gh1 = gh0, gh2 = gh0;   // waves 8-15 (P1->P4)
    Frag  bfr[12];                                         // waves 8-15 (P1->P4)
    float bir, biz, bin, bhr, bhz, bhn;                    // waves 8-15 (S->P4)
    Frag  obf[4];                                          // waves 0-3  (P3->P5)
    float ob;                                              // waves 0-3

    // ================ A: distributed frag conversion (waves 0-3, <=1 slot each) ================
    {
        const int gw = wv * 256 + (int)blockIdx.x;
        if (gw < FW_TOTAL) {
            Frag fr;
            if (gw < FW_FCW) {                       // w_hh
                int idx = gw - FW_WHH, t = idx >> 2, kf = idx & 3;
                loadWFrag(w_hh + (size_t)(t * 16 + arow) * kH + kf * 32 + kgrp, fr);
            } else if (gw < FW_WIH) {                // fc_w
                int idx = gw - FW_FCW, t = idx / 12, kf = idx % 12;
                loadWFrag(fc_w + (size_t)(t * 16 + arow) * 384 + kf * 32 + kgrp, fr);
            } else if (gw < FW_OUTW) {               // w_ih
                int idx = gw - FW_WIH, t = idx >> 2, kf = idx & 3;
                loadWFrag(w_ih + (size_t)(t * 16 + arow) * kH + kf * 32 + kgrp, fr);
            } else if (gw < FW_GX) {                 // out_w
                int idx = gw - FW_OUTW, t = idx >> 2, kf = idx & 3;
                loadWFrag(out_w + (size_t)(t * 16 + arow) * kH + kf * 32 + kgrp, fr);
            } else {                                 // gx weak-phase B-frags
                int idx = gw - FW_GX;
                int bb = idx >> 6, rem = idx & 63, t = rem >> 3, kf = rem & 7;
                int k0 = kf * 32 + kgrp;
                const float* gp = gx + ((size_t)bb * kN + k0) * kF + t * 16 + arow;
                fr.u[0] = pk(gp[0 * kF], gp[1 * kF]);
                fr.u[1] = pk(gp[2 * kF], gp[3 * kF]);
                fr.u[2] = pk(gp[4 * kF], gp[5 * kF]);
                fr.u[3] = pk(gp[6 * kF], gp[7 * kF]);
            }
            ws[(size_t)gw * 64 + lane] = *(uint4*)fr.u;
        }
    }

    // ================ S: stage LDS inputs + denom + bias prefetch (no ws reads) ================
    if (wv >= 8) {
        const int f = (wv - 8) * 16 + arow;
        bir = b_ih[f]; biz = b_ih[128 + f]; bin = b_ih[256 + f];
        bhr = b_hh[f]; bhz = b_hh[128 + f]; bhn = b_hh[256 + f];
    }
    {
        const int r = tid >> 7, c = tid & 127;
        const float* mrow = mask + ((size_t)b * kN + row0) * kN;
        maskb[r][c]       = cvt1(mrow[r * 256 + c]);
        maskb[r][c + 128] = cvt1(mrow[r * 256 + c + 128]);
        cmb[r][c] = cvt1(lx[((size_t)b * kN + row0) * kF + tid]);
        const int ki = key_idx[b];
        cmb[r][256 + c] = cvt1(gx[((size_t)b * kN + ki) * kF + c]);
        float hv = hstate[((size_t)b * kN + row0) * kH + tid];
        hf32[tid] = hv;
        hf16[r][c] = cvt1(hv);
    }
    if (wv < 8) {                          // denom in fp32 straight from global
        const float* mr = mask + ((size_t)b * kN + row0 + wv) * kN;
        float4 m4 = *(const float4*)(mr + lane * 4);
        float s = waveReduceAdd(m4.x + m4.y + m4.z + m4.w);
        if (lane == 0) denomInv[wv] = 1.0f / (s + 1e-6f);
    }

    // grid-wide sync: ws globally visible; also acts as block barrier for LDS staging
    cg::this_grid().sync();

    // ================ P1: weak (waves 0-7) || gh + gi-prefetch (waves 8-15) ================
    if (wv < 8) {
        Frag wkf[8];
        const uint4* wsf = ws + ((size_t)(FW_GX + b * 64 + wv * 8) * 64 + lane);
        #pragma unroll
        for (int kf = 0; kf < 8; ++kf) *(uint4*)wkf[kf].u = wsf[(size_t)kf * 64];
        f32x4 acc = {0.f, 0.f, 0.f, 0.f};
        #pragma unroll
        for (int kf = 0; kf < 8; ++kf) {
            Frag a;
            *(uint4*)a.u = *(const uint4*)&maskb[arow][kf * 32 + kgrp];
            acc = MFMA16(a.v, wkf[kf].v, acc);
        }
        const uint4* wsf2 = ws + ((size_t)(FW_FCW + wv * 12) * 64 + lane);
        #pragma unroll
        for (int kf = 0; kf < 12; ++kf) *(uint4*)fcf[kf].u = wsf2[(size_t)kf * 64];
        const int n0 = 16 * wv;
        if (lane < 32) {
            #pragma unroll
            for (int j = 0; j < 4; ++j) {
                int row = hi * 4 + j;
                cmb[row][128 + n0 + arow] = cvt1(acc[j] * denomInv[row]);
            }
        }
    } else {
        const int w2 = wv - 8;
        Frag hA[4];
        #pragma unroll
        for (int kf = 0; kf < 4; ++kf)
            *(uint4*)hA[kf].u = *(const uint4*)&hf16[arow][kf * 32 + kgrp];
        const uint4* p0 = ws + ((size_t)(FW_WHH + w2 * 4) * 64 + lane);
        const uint4* p1 = ws + ((size_t)(FW_WHH + (8 + w2) * 4) * 64 + lane);
        const uint4* p2 = ws + ((size_t)(FW_WHH + (16 + w2) * 4) * 64 + lane);
        #pragma unroll
        for (int kf = 0; kf < 4; ++kf) {
            Frag b0, b1, b2;
            *(uint4*)b0.u = p0[(size_t)kf * 64];
            *(uint4*)b1.u = p1[(size_t)kf * 64];
            *(uint4*)b2.u = p2[(size_t)kf * 64];
            gh0 = MFMA16(hA[kf].v, b0.v, gh0);
            gh1 = MFMA16(hA[kf].v, b1.v, gh1);
            gh2 = MFMA16(hA[kf].v, b2.v, gh2);
        }
        // prefetch gi B-frags (consumed P4; 2 barriers of slack)
        const uint4* q0 = ws + ((size_t)(FW_WIH + w2 * 4) * 64 + lane);
        const uint4* q1 = ws + ((size_t)(FW_WIH + (8 + w2) * 4) * 64 + lane);
        const uint4* q2 = ws + ((size_t)(FW_WIH + (16 + w2) * 4) * 64 + lane);
        #pragma unroll
        for (int kf = 0; kf < 4; ++kf) {
            *(uint4*)bfr[kf].u     = q0[(size_t)kf * 64];
            *(uint4*)bfr[4 + kf].u = q1[(size_t)kf * 64];
            *(uint4*)bfr[8 + kf].u = q2[(size_t)kf * 64];
        }
    }
    __syncthreads();   // bar1: weak cols in cmb ready

    // ================ P2: FC (waves 0-7) ================
    if (wv < 8) {
        f32x4 acc = {0.f, 0.f, 0.f, 0.f};
        #pragma unroll
        for (int kf = 0; kf < 12; ++kf) {
            Frag a;
            *(uint4*)a.u = *(const uint4*)&cmb[arow][kf * 32 + kgrp];
            acc = MFMA16(a.v, fcf[kf].v, acc);
        }
        const int n0 = 16 * wv;
        if (lane < 32) {
            #pragma unroll
            for (int j = 0; j < 4; ++j) {
                int row = hi * 4 + j;
                hb[row * 128 + n0 + arow] = acc[j];
            }
        }
    }
    __syncthreads();   // bar2: hb ready

    // ================ P3: LayerNorm + ReLU (waves 0-7) || out_w prefetch (waves 0-3) ================
    if (wv < 8) {
        int r = wv;
        float v0 = hb[r * 128 + lane]      + fc_b[lane];
        float v1 = hb[r * 128 + lane + 64] + fc_b[lane + 64];
        float s  = waveReduceAdd(v0 + v1);
        float ss = waveReduceAdd(v0 * v0 + v1 * v1);
        float mu   = s * (1.0f / 128.0f);
        float var  = ss * (1.0f / 128.0f) - mu * mu;
        float rstd = rsqrtf(var + 1e-5f);
        float x0 = fmaxf((v0 - mu) * rstd * ln_g[lane] + ln_b[lane], 0.f);
        float x1 = fmaxf((v1 - mu) * rstd * ln_g[lane + 64] + ln_b[lane + 64], 0.f);
        xb16[r][lane]      = cvt1(x0);
        xb16[r][lane + 64] = cvt1(x1);
        if (wv < 4) {
            const uint4* po = ws + ((size_t)(FW_OUTW + wv * 4) * 64 + lane);
            #pragma unroll
            for (int kf = 0; kf < 4; ++kf)
                *(uint4*)obf[kf].u = po[(size_t)kf * 64];
            ob = out_b[16 * wv + arow];
        }
    }
    __syncthreads();   // bar3: xb16 ready

    // ================ P4: gi + in-register gates (waves 8-15) ================
    if (wv >= 8) {
        const int w2 = wv - 8;
        Frag xA[4];
        #pragma unroll
        for (int kf = 0; kf < 4; ++kf)
            *(uint4*)xA[kf].u = *(const uint4*)&xb16[arow][kf * 32 + kgrp];
        f32x4 gi0 = {0.f, 0.f, 0.f, 0.f}, gi1 = gi0, gi2 = gi0;
        #pragma unroll
        for (int kf = 0; kf < 4; ++kf) {
            gi0 = MFMA16(xA[kf].v, bfr[kf].v, gi0);
            gi1 = MFMA16(xA[kf].v, bfr[4 + kf].v, gi1);
            gi2 = MFMA16(xA[kf].v, bfr[8 + kf].v, gi2);
        }
        if (lane < 32) {
            const int f = w2 * 16 + arow;
            #pragma unroll
            for (int j = 0; j < 4; ++j) {
                int row = hi * 4 + j;
                float rg = sigm(gi0[j] + bir + gh0[j] + bhr);
                float zg = sigm(gi1[j] + biz + gh1[j] + bhz);
                float ng = tanh_fast(gi2[j] + bin + rg * (gh2[j] + bhn));
                float hprev = hf32[row * 128 + f];
                float hnew = (1.0f - zg) * ng + zg * hprev;
                hnb16[row][f] = cvt1(hnew);
                out[kOut0 + ((size_t)(b * kN + row0 + row)) * kH + f] = hnew;
            }
        }
    }
    __syncthreads();   // bar4: hnb16 ready

    // ================ P5: out head (waves 0-3) ================
    if (wv < 4) {
        f32x4 acc = {0.f, 0.f, 0.f, 0.f};
        #pragma unroll
        for (int kf = 0; kf < 4; ++kf) {
            Frag a;
            *(uint4*)a.u = *(const uint4*)&hnb16[arow][kf * 32 + kgrp];
            acc = MFMA16(a.v, obf[kf].v, acc);
        }
        if (lane < 32) {
            const int n0 = 16 * wv;
            #pragma unroll
            for (int j = 0; j < 4; ++j) {
                int row = hi * 4 + j;
                out[((size_t)(b * kN + row0 + row)) * kO + n0 + arow] = acc[j] + ob;
            }
        }
    }
}

} // namespace

extern "C" void kernel_launch(void* const* d_in, const int* in_sizes, int n_in,
                              void* d_out, int out_size, void* d_ws, size_t ws_size,
                              hipStream_t stream) {
    const float* lx      = (const float*)d_in[0];
    const float* gx      = (const float*)d_in[1];
    const float* mask    = (const float*)d_in[2];
    const int*   key_idx = (const int*)  d_in[3];
    const float* hs      = (const float*)d_in[4];
    const float* fc_w    = (const float*)d_in[5];
    const float* fc_b    = (const float*)d_in[6];
    const float* ln_g    = (const float*)d_in[7];
    const float* ln_b    = (const float*)d_in[8];
    const float* w_ih    = (const float*)d_in[9];
    const float* w_hh    = (const float*)d_in[10];
    const float* b_ih    = (const float*)d_in[11];
    const float* b_hh    = (const float*)d_in[12];
    const float* out_w   = (const float*)d_in[13];
    const float* out_b   = (const float*)d_in[14];
    float* out = (float*)d_out;
    uint4* ws = (uint4*)d_ws;   // needs 816 KB

    void* args[17] = {
        (void*)&lx, (void*)&gx, (void*)&mask, (void*)&key_idx, (void*)&hs,
        (void*)&fc_w, (void*)&fc_b, (void*)&ln_g, (void*)&ln_b,
        (void*)&w_ih, (void*)&w_hh, (void*)&b_ih, (void*)&b_hh,
        (void*)&out_w, (void*)&out_b, (void*)&ws, (void*)&out
    };
    hipLaunchCooperativeKernel(weak_tie_all,
                               dim3(kB * kN / kR),   // 256 blocks, 1 per CU
                               dim3(kTPB),           // 1024 threads = 16 waves
                               args, 0, stream);
}

// Round 12
// 34.720 us; speedup vs baseline: 1.5893x; 1.5893x over previous
//
#include <hip/hip_runtime.h>

namespace {

typedef unsigned short ushort_t;
typedef unsigned int uint_t;
typedef __attribute__((ext_vector_type(8))) short short8v;   // 8 bf16 (4 VGPRs)
typedef __attribute__((ext_vector_type(4))) float f32x4;     // MFMA accumulator

constexpr int kB = 8, kN = 256, kF = 128, kH = 128, kO = 64;
constexpr int kR = 8;              // real rows per block (16-row MFMA tiles, rows 8-15 garbage/discarded)
constexpr int kTPB = 1024;         // 16 waves
constexpr int kOut0 = kB * kN * kO;

// d_ws frag-slot bases (each slot = 64 lanes x 16B = 1KB, holds one B-frag)
constexpr int FW_WHH  = 0;     // w_hh : 24 tiles x 4 kf  = 96
constexpr int FW_FCW  = 96;    // fc_w :  8 tiles x 12 kf = 96
constexpr int FW_WIH  = 192;   // w_ih : 24 tiles x 4 kf  = 96
constexpr int FW_OUTW = 288;   // out_w:  4 tiles x 4 kf  = 16
constexpr int FW_GX   = 304;   // gx   :  8 b x 8 tiles x 8 kf = 512
constexpr int FW_TOTAL = 816;  // 816 KB total in d_ws

union Frag {
    uint_t  u[4];
    short8v v;
};

__device__ __forceinline__ float waveReduceAdd(float v) {
    v += __shfl_xor(v, 1);
    v += __shfl_xor(v, 2);
    v += __shfl_xor(v, 4);
    v += __shfl_xor(v, 8);
    v += __shfl_xor(v, 16);
    v += __shfl_xor(v, 32);
    return v;
}

__device__ __forceinline__ ushort_t cvt1(float f) {
    return (ushort_t)((__float_as_uint(f) + 0x8000u) >> 16);
}
__device__ __forceinline__ uint_t pk(float f0, float f1) {
    uint_t b0 = __float_as_uint(f0) + 0x8000u;
    uint_t b1 = __float_as_uint(f1) + 0x8000u;
    return (b1 & 0xFFFF0000u) | (b0 >> 16);
}
__device__ __forceinline__ float sigm(float x) {
    return __builtin_amdgcn_rcpf(1.0f + __expf(-x));
}
__device__ __forceinline__ float tanh_fast(float x) {
    x = fminf(fmaxf(x, -15.0f), 15.0f);
    float e = __expf(2.0f * x);
    return (e - 1.0f) * __builtin_amdgcn_rcpf(e + 1.0f);
}
__device__ __forceinline__ void loadWFrag(const float* __restrict__ p, Frag& b) {
    float4 lo = *(const float4*)p;
    float4 hi = *(const float4*)(p + 4);
    b.u[0] = pk(lo.x, lo.y);
    b.u[1] = pk(lo.z, lo.w);
    b.u[2] = pk(hi.x, hi.y);
    b.u[3] = pk(hi.z, hi.w);
}

// ---------------- pre-pass: build bf16 B-frags in d_ws (816 KB) ----------------
__global__ __launch_bounds__(256) void convert_frags(
    const float* __restrict__ gx, const float* __restrict__ fc_w,
    const float* __restrict__ w_ih, const float* __restrict__ w_hh,
    const float* __restrict__ out_w, uint4* __restrict__ ws)
{
    const int gw = (int)((blockIdx.x * 256 + threadIdx.x) >> 6);
    if (gw >= FW_TOTAL) return;
    const int lane = threadIdx.x & 63;
    const int arow = lane & 15;
    const int kgrp = (lane >> 4) * 8;
    Frag fr;
    if (gw < FW_FCW) {                       // w_hh
        int idx = gw - FW_WHH, t = idx >> 2, kf = idx & 3;
        loadWFrag(w_hh + (size_t)(t * 16 + arow) * kH + kf * 32 + kgrp, fr);
    } else if (gw < FW_WIH) {                // fc_w
        int idx = gw - FW_FCW, t = idx / 12, kf = idx % 12;
        loadWFrag(fc_w + (size_t)(t * 16 + arow) * 384 + kf * 32 + kgrp, fr);
    } else if (gw < FW_OUTW) {               // w_ih
        int idx = gw - FW_WIH, t = idx >> 2, kf = idx & 3;
        loadWFrag(w_ih + (size_t)(t * 16 + arow) * kH + kf * 32 + kgrp, fr);
    } else if (gw < FW_GX) {                 // out_w
        int idx = gw - FW_OUTW, t = idx >> 2, kf = idx & 3;
        loadWFrag(out_w + (size_t)(t * 16 + arow) * kH + kf * 32 + kgrp, fr);
    } else {                                 // gx weak-phase B-frags
        int idx = gw - FW_GX;
        int bb = idx >> 6, rem = idx & 63, t = rem >> 3, kf = rem & 7;
        int k0 = kf * 32 + kgrp;
        const float* gp = gx + ((size_t)bb * kN + k0) * kF + t * 16 + arow;
        fr.u[0] = pk(gp[0 * kF], gp[1 * kF]);
        fr.u[1] = pk(gp[2 * kF], gp[3 * kF]);
        fr.u[2] = pk(gp[4 * kF], gp[5 * kF]);
        fr.u[3] = pk(gp[6 * kF], gp[7 * kF]);
    }
    ws[(size_t)gw * 64 + lane] = *(uint4*)fr.u;
}

#define MFMA16(A, B, C) __builtin_amdgcn_mfma_f32_16x16x32_bf16((A), (B), (C), 0, 0, 0)

// ---------------- fused main kernel: 8 rows/block, 256 blocks, 5 barriers (R7 structure) ----------------
__global__ __launch_bounds__(kTPB, 4) void weak_tie_fused(
    const float* __restrict__ lx, const float* __restrict__ gx,
    const float* __restrict__ mask, const int* __restrict__ key_idx,
    const float* __restrict__ hstate,
    const float* __restrict__ fc_b,
    const float* __restrict__ ln_g, const float* __restrict__ ln_b,
    const float* __restrict__ b_ih, const float* __restrict__ b_hh,
    const float* __restrict__ out_b,
    const uint4* __restrict__ ws,
    float* __restrict__ out)
{
    // rows 8-15 of the 16-row A-tiles are garbage; their C-rows are discarded (lane<32 guards).
    __shared__ __align__(16) ushort_t maskb[16][264];
    __shared__ __align__(16) ushort_t cmb[16][392];     // [lx | weak | key]
    __shared__ __align__(16) ushort_t hf16[16][136];
    __shared__ __align__(16) ushort_t xb16[16][136];
    __shared__ __align__(16) ushort_t hnb16[16][136];
    __shared__ __align__(16) float hf32[kR * kH];
    __shared__ __align__(16) float hb[kR * kH];
    __shared__ float denomInv[kR];

    const int tid  = threadIdx.x;
    const int b    = blockIdx.x >> 5;
    const int row0 = (blockIdx.x & 31) * kR;
    const int lane = tid & 63;
    const int wv   = tid >> 6;            // 0..15
    const int arow = lane & 15;
    const int kgrp = (lane >> 4) * 8;
    const int hi   = lane >> 4;           // 0..3 (C-rows valid only for hi<2)

    // persistent per-wave register state
    Frag  wkf[8];                                          // waves 0-7  (S->P1)
    Frag  fcf[12];                                         // waves 0-7  (P1->P2)
    float fb0, fb1, g0, g1, lb0, lb1;                      // waves 0-7  (S->P3) [hoisted]
    f32x4 gh0 = {0.f,0.f,0.f,0.f}, gh1 = gh0, gh2 = gh0;   // waves 8-15 (P1->P4)
    Frag  bfr[12];                                         // waves 8-15 (P1->P4)
    float bir, biz, bin, bhr, bhz, bhn;                    // waves 8-15 (S->P4)
    Frag  obf[4];                                          // waves 0-3  (S->P5) [hoisted]
    float ob;                                              // waves 0-3

    // ================ S: stage + denom + prefetches ================
    if (wv < 8) {
        const uint4* wsf = ws + ((size_t)(FW_GX + b * 64 + wv * 8) * 64 + lane);
        #pragma unroll
        for (int kf = 0; kf < 8; ++kf) *(uint4*)wkf[kf].u = wsf[(size_t)kf * 64];
        // LN params hoisted out of P3
        fb0 = fc_b[lane]; fb1 = fc_b[lane + 64];
        g0  = ln_g[lane]; g1  = ln_g[lane + 64];
        lb0 = ln_b[lane]; lb1 = ln_b[lane + 64];
        if (wv < 4) {
            // out head B-frags hoisted out of P3
            const uint4* po = ws + ((size_t)(FW_OUTW + wv * 4) * 64 + lane);
            #pragma unroll
            for (int kf = 0; kf < 4; ++kf)
                *(uint4*)obf[kf].u = po[(size_t)kf * 64];
            ob = out_b[16 * wv + arow];
        }
    } else {
        const int f = (wv - 8) * 16 + arow;
        bir = b_ih[f]; biz = b_ih[128 + f]; bin = b_ih[256 + f];
        bhr = b_hh[f]; bhz = b_hh[128 + f]; bhn = b_hh[256 + f];
    }
    {
        const int r = tid >> 7, c = tid & 127;
        const float* mrow = mask + ((size_t)b * kN + row0) * kN;
        maskb[r][c]       = cvt1(mrow[r * 256 + c]);
        maskb[r][c + 128] = cvt1(mrow[r * 256 + c + 128]);
        cmb[r][c] = cvt1(lx[((size_t)b * kN + row0) * kF + tid]);
        const int ki = key_idx[b];
        cmb[r][256 + c] = cvt1(gx[((size_t)b * kN + ki) * kF + c]);
        float hv = hstate[((size_t)b * kN + row0) * kH + tid];
        hf32[tid] = hv;
        hf16[r][c] = cvt1(hv);
    }
    if (wv < 8) {                          // denom in fp32 straight from global
        const float* mr = mask + ((size_t)b * kN + row0 + wv) * kN;
        float4 m4 = *(const float4*)(mr + lane * 4);
        float s = waveReduceAdd(m4.x + m4.y + m4.z + m4.w);
        if (lane == 0) denomInv[wv] = 1.0f / (s + 1e-6f);
    }
    __syncthreads();   // bar0: LDS tiles + denom ready

    // ================ P1: weak (waves 0-7) || gh + gi-prefetch (waves 8-15) ================
    if (wv < 8) {
        f32x4 acc = {0.f, 0.f, 0.f, 0.f};
        #pragma unroll
        for (int kf = 0; kf < 8; ++kf) {
            Frag a;
            *(uint4*)a.u = *(const uint4*)&maskb[arow][kf * 32 + kgrp];
            acc = MFMA16(a.v, wkf[kf].v, acc);
        }
        const uint4* wsf = ws + ((size_t)(FW_FCW + wv * 12) * 64 + lane);
        #pragma unroll
        for (int kf = 0; kf < 12; ++kf) *(uint4*)fcf[kf].u = wsf[(size_t)kf * 64];
        const int n0 = 16 * wv;
        if (lane < 32) {
            #pragma unroll
            for (int j = 0; j < 4; ++j) {
                int row = hi * 4 + j;
                cmb[row][128 + n0 + arow] = cvt1(acc[j] * denomInv[row]);
            }
        }
    } else {
        const int w2 = wv - 8;
        Frag hA[4];
        #pragma unroll
        for (int kf = 0; kf < 4; ++kf)
            *(uint4*)hA[kf].u = *(const uint4*)&hf16[arow][kf * 32 + kgrp];
        const uint4* p0 = ws + ((size_t)(FW_WHH + w2 * 4) * 64 + lane);
        const uint4* p1 = ws + ((size_t)(FW_WHH + (8 + w2) * 4) * 64 + lane);
        const uint4* p2 = ws + ((size_t)(FW_WHH + (16 + w2) * 4) * 64 + lane);
        #pragma unroll
        for (int kf = 0; kf < 4; ++kf) {
            Frag b0, b1, b2;
            *(uint4*)b0.u = p0[(size_t)kf * 64];
            *(uint4*)b1.u = p1[(size_t)kf * 64];
            *(uint4*)b2.u = p2[(size_t)kf * 64];
            gh0 = MFMA16(hA[kf].v, b0.v, gh0);
            gh1 = MFMA16(hA[kf].v, b1.v, gh1);
            gh2 = MFMA16(hA[kf].v, b2.v, gh2);
        }
        // prefetch gi B-frags (consumed P4; 2 barriers of slack)
        const uint4* q0 = ws + ((size_t)(FW_WIH + w2 * 4) * 64 + lane);
        const uint4* q1 = ws + ((size_t)(FW_WIH + (8 + w2) * 4) * 64 + lane);
        const uint4* q2 = ws + ((size_t)(FW_WIH + (16 + w2) * 4) * 64 + lane);
        #pragma unroll
        for (int kf = 0; kf < 4; ++kf) {
            *(uint4*)bfr[kf].u     = q0[(size_t)kf * 64];
            *(uint4*)bfr[4 + kf].u = q1[(size_t)kf * 64];
            *(uint4*)bfr[8 + kf].u = q2[(size_t)kf * 64];
        }
    }
    __syncthreads();   // bar1: weak cols in cmb ready

    // ================ P2: FC (waves 0-7) ================
    if (wv < 8) {
        f32x4 acc = {0.f, 0.f, 0.f, 0.f};
        #pragma unroll
        for (int kf = 0; kf < 12; ++kf) {
            Frag a;
            *(uint4*)a.u = *(const uint4*)&cmb[arow][kf * 32 + kgrp];
            acc = MFMA16(a.v, fcf[kf].v, acc);
        }
        const int n0 = 16 * wv;
        if (lane < 32) {
            #pragma unroll
            for (int j = 0; j < 4; ++j) {
                int row = hi * 4 + j;
                hb[row * 128 + n0 + arow] = acc[j];
            }
        }
    }
    __syncthreads();   // bar2: hb ready

    // ================ P3: LayerNorm + ReLU (waves 0-7, one row each) ================
    if (wv < 8) {
        int r = wv;
        float v0 = hb[r * 128 + lane]      + fb0;
        float v1 = hb[r * 128 + lane + 64] + fb1;
        float s  = waveReduceAdd(v0 + v1);
        float ss = waveReduceAdd(v0 * v0 + v1 * v1);
        float mu   = s * (1.0f / 128.0f);
        float var  = ss * (1.0f / 128.0f) - mu * mu;
        float rstd = rsqrtf(var + 1e-5f);
        float x0 = fmaxf((v0 - mu) * rstd * g0 + lb0, 0.f);
        float x1 = fmaxf((v1 - mu) * rstd * g1 + lb1, 0.f);
        xb16[r][lane]      = cvt1(x0);
        xb16[r][lane + 64] = cvt1(x1);
    }
    __syncthreads();   // bar3: xb16 ready

    // ================ P4: gi + in-register gates (waves 8-15) ================
    if (wv >= 8) {
        const int w2 = wv - 8;
        Frag xA[4];
        #pragma unroll
        for (int kf = 0; kf < 4; ++kf)
            *(uint4*)xA[kf].u = *(const uint4*)&xb16[arow][kf * 32 + kgrp];
        f32x4 gi0 = {0.f, 0.f, 0.f, 0.f}, gi1 = gi0, gi2 = gi0;
        #pragma unroll
        for (int kf = 0; kf < 4; ++kf) {
            gi0 = MFMA16(xA[kf].v, bfr[kf].v, gi0);
            gi1 = MFMA16(xA[kf].v, bfr[4 + kf].v, gi1);
            gi2 = MFMA16(xA[kf].v, bfr[8 + kf].v, gi2);
        }
        if (lane < 32) {
            const int f = w2 * 16 + arow;
            #pragma unroll
            for (int j = 0; j < 4; ++j) {
                int row = hi * 4 + j;
                float rg = sigm(gi0[j] + bir + gh0[j] + bhr);
                float zg = sigm(gi1[j] + biz + gh1[j] + bhz);
                float ng = tanh_fast(gi2[j] + bin + rg * (gh2[j] + bhn));
                float hprev = hf32[row * 128 + f];
                float hnew = (1.0f - zg) * ng + zg * hprev;
                hnb16[row][f] = cvt1(hnew);
                out[kOut0 + ((size_t)(b * kN + row0 + row)) * kH + f] = hnew;
            }
        }
    }
    __syncthreads();   // bar4: hnb16 ready

    // ================ P5: out head (waves 0-3) ================
    if (wv < 4) {
        f32x4 acc = {0.f, 0.f, 0.f, 0.f};
        #pragma unroll
        for (int kf = 0; kf < 4; ++kf) {
            Frag a;
            *(uint4*)a.u = *(const uint4*)&hnb16[arow][kf * 32 + kgrp];
            acc = MFMA16(a.v, obf[kf].v, acc);
        }
        if (lane < 32) {
            const int n0 = 16 * wv;
            #pragma unroll
            for (int j = 0; j < 4; ++j) {
                int row = hi * 4 + j;
                out[((size_t)(b * kN + row0 + row)) * kO + n0 + arow] = acc[j] + ob;
            }
        }
    }
}

} // namespace

extern "C" void kernel_launch(void* const* d_in, const int* in_sizes, int n_in,
                              void* d_out, int out_size, void* d_ws, size_t ws_size,
                              hipStream_t stream) {
    const float* lx      = (const float*)d_in[0];
    const float* gx      = (const float*)d_in[1];
    const float* mask    = (const float*)d_in[2];
    const int*   key_idx = (const int*)  d_in[3];
    const float* hs      = (const float*)d_in[4];
    const float* fc_w    = (const float*)d_in[5];
    const float* fc_b    = (const float*)d_in[6];
    const float* ln_g    = (const float*)d_in[7];
    const float* ln_b    = (const float*)d_in[8];
    const float* w_ih    = (const float*)d_in[9];
    const float* w_hh    = (const float*)d_in[10];
    const float* b_ih    = (const float*)d_in[11];
    const float* b_hh    = (const float*)d_in[12];
    const float* out_w   = (const float*)d_in[13];
    const float* out_b   = (const float*)d_in[14];
    float* out = (float*)d_out;
    uint4* ws = (uint4*)d_ws;   // needs 816 KB

    hipLaunchKernelGGL(convert_frags, dim3((FW_TOTAL * 64) / 256), dim3(256), 0, stream,
                       gx, fc_w, w_ih, w_hh, out_w, ws);

    dim3 grid(kB * kN / kR);   // 256 blocks
    dim3 block(kTPB);          // 1024 threads = 16 waves
    hipLaunchKernelGGL(weak_tie_fused, grid, block, 0, stream,
                       lx, gx, mask, key_idx, hs,
                       fc_b, ln_g, ln_b,
                       b_ih, b_hh, out_b,
                       (const uint4*)ws, out);
}

// Round 13
// 18.315 us; speedup vs baseline: 3.0129x; 1.8958x over previous
//
#include <hip/hip_runtime.h>

namespace {

typedef unsigned short ushort_t;
typedef unsigned int uint_t;
typedef __attribute__((ext_vector_type(8))) short short8v;   // 8 bf16 (4 VGPRs)
typedef __attribute__((ext_vector_type(4))) float f32x4;     // MFMA accumulator

constexpr int kB = 8, kN = 256, kF = 128, kH = 128, kO = 64;
constexpr int kR = 8;              // real rows per block (16-row MFMA tiles, rows 8-15 garbage/discarded)
constexpr int kTPB = 1024;         // 16 waves
constexpr int kOut0 = kB * kN * kO;

// d_ws frag-slot bases (each slot = 64 lanes x 16B = 1KB, holds one B-frag)
constexpr int FW_WHH  = 0;     // w_hh : 24 tiles x 4 kf  = 96
constexpr int FW_FCW  = 96;    // fc_w :  8 tiles x 12 kf = 96
constexpr int FW_WIH  = 192;   // w_ih : 24 tiles x 4 kf  = 96
constexpr int FW_OUTW = 288;   // out_w:  4 tiles x 4 kf  = 16
constexpr int FW_GX   = 304;   // gx   :  8 b x 8 tiles x 8 kf = 512
constexpr int FW_TOTAL = 816;  // 816 KB total in d_ws

union Frag {
    uint_t  u[4];
    short8v v;
};

__device__ __forceinline__ float waveReduceAdd(float v) {
    v += __shfl_xor(v, 1);
    v += __shfl_xor(v, 2);
    v += __shfl_xor(v, 4);
    v += __shfl_xor(v, 8);
    v += __shfl_xor(v, 16);
    v += __shfl_xor(v, 32);
    return v;
}

__device__ __forceinline__ ushort_t cvt1(float f) {
    return (ushort_t)((__float_as_uint(f) + 0x8000u) >> 16);
}
__device__ __forceinline__ uint_t pk(float f0, float f1) {
    uint_t b0 = __float_as_uint(f0) + 0x8000u;
    uint_t b1 = __float_as_uint(f1) + 0x8000u;
    return (b1 & 0xFFFF0000u) | (b0 >> 16);
}
__device__ __forceinline__ float sigm(float x) {
    return __builtin_amdgcn_rcpf(1.0f + __expf(-x));
}
__device__ __forceinline__ float tanh_fast(float x) {
    x = fminf(fmaxf(x, -15.0f), 15.0f);
    float e = __expf(2.0f * x);
    return (e - 1.0f) * __builtin_amdgcn_rcpf(e + 1.0f);
}
__device__ __forceinline__ void loadWFrag(const float* __restrict__ p, Frag& b) {
    float4 lo = *(const float4*)p;
    float4 hi = *(const float4*)(p + 4);
    b.u[0] = pk(lo.x, lo.y);
    b.u[1] = pk(lo.z, lo.w);
    b.u[2] = pk(hi.x, hi.y);
    b.u[3] = pk(hi.z, hi.w);
}

// ---------------- pre-pass: build bf16 B-frags in d_ws (816 KB) ----------------
__global__ __launch_bounds__(256) void convert_frags(
    const float* __restrict__ gx, const float* __restrict__ fc_w,
    const float* __restrict__ w_ih, const float* __restrict__ w_hh,
    const float* __restrict__ out_w, uint4* __restrict__ ws)
{
    const int gw = (int)((blockIdx.x * 256 + threadIdx.x) >> 6);
    if (gw >= FW_TOTAL) return;
    const int lane = threadIdx.x & 63;
    const int arow = lane & 15;
    const int kgrp = (lane >> 4) * 8;
    Frag fr;
    if (gw < FW_FCW) {                       // w_hh
        int idx = gw - FW_WHH, t = idx >> 2, kf = idx & 3;
        loadWFrag(w_hh + (size_t)(t * 16 + arow) * kH + kf * 32 + kgrp, fr);
    } else if (gw < FW_WIH) {                // fc_w
        int idx = gw - FW_FCW, t = idx / 12, kf = idx % 12;
        loadWFrag(fc_w + (size_t)(t * 16 + arow) * 384 + kf * 32 + kgrp, fr);
    } else if (gw < FW_OUTW) {               // w_ih
        int idx = gw - FW_WIH, t = idx >> 2, kf = idx & 3;
        loadWFrag(w_ih + (size_t)(t * 16 + arow) * kH + kf * 32 + kgrp, fr);
    } else if (gw < FW_GX) {                 // out_w
        int idx = gw - FW_OUTW, t = idx >> 2, kf = idx & 3;
        loadWFrag(out_w + (size_t)(t * 16 + arow) * kH + kf * 32 + kgrp, fr);
    } else {                                 // gx weak-phase B-frags
        int idx = gw - FW_GX;
        int bb = idx >> 6, rem = idx & 63, t = rem >> 3, kf = rem & 7;
        int k0 = kf * 32 + kgrp;
        const float* gp = gx + ((size_t)bb * kN + k0) * kF + t * 16 + arow;
        fr.u[0] = pk(gp[0 * kF], gp[1 * kF]);
        fr.u[1] = pk(gp[2 * kF], gp[3 * kF]);
        fr.u[2] = pk(gp[4 * kF], gp[5 * kF]);
        fr.u[3] = pk(gp[6 * kF], gp[7 * kF]);
    }
    ws[(size_t)gw * 64 + lane] = *(uint4*)fr.u;
}

#define MFMA16(A, B, C) __builtin_amdgcn_mfma_f32_16x16x32_bf16((A), (B), (C), 0, 0, 0)

// ---------------- fused main kernel: 8 rows/block, 256 blocks, 5 barriers (R7, best=18.4us) ----------------
__global__ __launch_bounds__(kTPB, 4) void weak_tie_fused(
    const float* __restrict__ lx, const float* __restrict__ gx,
    const float* __restrict__ mask, const int* __restrict__ key_idx,
    const float* __restrict__ hstate,
    const float* __restrict__ fc_b,
    const float* __restrict__ ln_g, const float* __restrict__ ln_b,
    const float* __restrict__ b_ih, const float* __restrict__ b_hh,
    const float* __restrict__ out_b,
    const uint4* __restrict__ ws,
    float* __restrict__ out)
{
    // rows 8-15 of the 16-row A-tiles are garbage; their C-rows are discarded (lane<32 guards).
    // NOTE: do NOT hoist extra state across barriers — the unified live set sits
    // just under the 128-VGPR residency cliff for 16-wave blocks (R12 spilled, 2x).
    __shared__ __align__(16) ushort_t maskb[16][264];
    __shared__ __align__(16) ushort_t cmb[16][392];     // [lx | weak | key]
    __shared__ __align__(16) ushort_t hf16[16][136];
    __shared__ __align__(16) ushort_t xb16[16][136];
    __shared__ __align__(16) ushort_t hnb16[16][136];
    __shared__ __align__(16) float hf32[kR * kH];
    __shared__ __align__(16) float hb[kR * kH];
    __shared__ float denomInv[kR];

    const int tid  = threadIdx.x;
    const int b    = blockIdx.x >> 5;
    const int row0 = (blockIdx.x & 31) * kR;
    const int lane = tid & 63;
    const int wv   = tid >> 6;            // 0..15
    const int arow = lane & 15;
    const int kgrp = (lane >> 4) * 8;
    const int hi   = lane >> 4;           // 0..3 (C-rows valid only for hi<2)

    // ================ S: stage + denom + weak-frag prefetch ================
    Frag wkf[8];                           // waves 0-7: weak B-frags (live S->P1)
    if (wv < 8) {
        const uint4* wsf = ws + ((size_t)(FW_GX + b * 64 + wv * 8) * 64 + lane);
        #pragma unroll
        for (int kf = 0; kf < 8; ++kf) *(uint4*)wkf[kf].u = wsf[(size_t)kf * 64];
    }
    {
        const int r = tid >> 7, c = tid & 127;
        const float* mrow = mask + ((size_t)b * kN + row0) * kN;
        maskb[r][c]       = cvt1(mrow[r * 256 + c]);
        maskb[r][c + 128] = cvt1(mrow[r * 256 + c + 128]);
        cmb[r][c] = cvt1(lx[((size_t)b * kN + row0) * kF + tid]);
        const int ki = key_idx[b];
        cmb[r][256 + c] = cvt1(gx[((size_t)b * kN + ki) * kF + c]);
        float hv = hstate[((size_t)b * kN + row0) * kH + tid];
        hf32[tid] = hv;
        hf16[r][c] = cvt1(hv);
    }
    if (wv < 8) {                          // denom in fp32 straight from global
        const float* mr = mask + ((size_t)b * kN + row0 + wv) * kN;
        float4 m4 = *(const float4*)(mr + lane * 4);
        float s = waveReduceAdd(m4.x + m4.y + m4.z + m4.w);
        if (lane == 0) denomInv[wv] = 1.0f / (s + 1e-6f);
    }
    __syncthreads();

    // ================ P1: weak (waves 0-7) || gh->regs (waves 8-15) ================
    f32x4 gh0 = {0.f, 0.f, 0.f, 0.f}, gh1 = gh0, gh2 = gh0;   // waves 8-15, live P1->P4
    Frag fcf[12];                          // waves 0-7: FC B-frags (live P1->P2)
    if (wv < 8) {
        f32x4 acc = {0.f, 0.f, 0.f, 0.f};
        #pragma unroll
        for (int kf = 0; kf < 8; ++kf) {
            Frag a;
            *(uint4*)a.u = *(const uint4*)&maskb[arow][kf * 32 + kgrp];
            acc = MFMA16(a.v, wkf[kf].v, acc);
        }
        const uint4* wsf = ws + ((size_t)(FW_FCW + wv * 12) * 64 + lane);
        #pragma unroll
        for (int kf = 0; kf < 12; ++kf) *(uint4*)fcf[kf].u = wsf[(size_t)kf * 64];
        const int n0 = 16 * wv;
        if (lane < 32) {
            #pragma unroll
            for (int j = 0; j < 4; ++j) {
                int row = hi * 4 + j;
                cmb[row][128 + n0 + arow] = cvt1(acc[j] * denomInv[row]);
            }
        }
    } else {
        const int w2 = wv - 8;
        Frag hA[4];
        #pragma unroll
        for (int kf = 0; kf < 4; ++kf)
            *(uint4*)hA[kf].u = *(const uint4*)&hf16[arow][kf * 32 + kgrp];
        const uint4* p0 = ws + ((size_t)(FW_WHH + w2 * 4) * 64 + lane);
        const uint4* p1 = ws + ((size_t)(FW_WHH + (8 + w2) * 4) * 64 + lane);
        const uint4* p2 = ws + ((size_t)(FW_WHH + (16 + w2) * 4) * 64 + lane);
        #pragma unroll
        for (int kf = 0; kf < 4; ++kf) {
            Frag b0, b1, b2;
            *(uint4*)b0.u = p0[(size_t)kf * 64];
            *(uint4*)b1.u = p1[(size_t)kf * 64];
            *(uint4*)b2.u = p2[(size_t)kf * 64];
            gh0 = MFMA16(hA[kf].v, b0.v, gh0);
            gh1 = MFMA16(hA[kf].v, b1.v, gh1);
            gh2 = MFMA16(hA[kf].v, b2.v, gh2);
        }
    }
    __syncthreads();

    // ================ P2: FC (waves 0-7) || gi-frag prefetch (waves 8-15) ================
    Frag bfr[12];                          // waves 8-15: gi B-frags (live P2->P4)
    if (wv < 8) {
        f32x4 acc = {0.f, 0.f, 0.f, 0.f};
        #pragma unroll
        for (int kf = 0; kf < 12; ++kf) {
            Frag a;
            *(uint4*)a.u = *(const uint4*)&cmb[arow][kf * 32 + kgrp];
            acc = MFMA16(a.v, fcf[kf].v, acc);
        }
        const int n0 = 16 * wv;
        if (lane < 32) {
            #pragma unroll
            for (int j = 0; j < 4; ++j) {
                int row = hi * 4 + j;
                hb[row * 128 + n0 + arow] = acc[j];
            }
        }
    } else {
        const int w2 = wv - 8;
        const uint4* p0 = ws + ((size_t)(FW_WIH + w2 * 4) * 64 + lane);
        const uint4* p1 = ws + ((size_t)(FW_WIH + (8 + w2) * 4) * 64 + lane);
        const uint4* p2 = ws + ((size_t)(FW_WIH + (16 + w2) * 4) * 64 + lane);
        #pragma unroll
        for (int kf = 0; kf < 4; ++kf) {
            *(uint4*)bfr[kf].u     = p0[(size_t)kf * 64];
            *(uint4*)bfr[4 + kf].u = p1[(size_t)kf * 64];
            *(uint4*)bfr[8 + kf].u = p2[(size_t)kf * 64];
        }
    }
    __syncthreads();

    // ================ P3: LayerNorm + ReLU (waves 0-7, one row each) ================
    if (wv < 8) {
        int r = wv;
        float v0 = hb[r * 128 + lane]      + fc_b[lane];
        float v1 = hb[r * 128 + lane + 64] + fc_b[lane + 64];
        float s  = waveReduceAdd(v0 + v1);
        float ss = waveReduceAdd(v0 * v0 + v1 * v1);
        float mu   = s * (1.0f / 128.0f);
        float var  = ss * (1.0f / 128.0f) - mu * mu;
        float rstd = rsqrtf(var + 1e-5f);
        float x0 = fmaxf((v0 - mu) * rstd * ln_g[lane] + ln_b[lane], 0.f);
        float x1 = fmaxf((v1 - mu) * rstd * ln_g[lane + 64] + ln_b[lane + 64], 0.f);
        xb16[r][lane]      = cvt1(x0);
        xb16[r][lane + 64] = cvt1(x1);
    }
    __syncthreads();

    // ================ P4: gi + in-register gates (waves 8-15) || out_w prefetch (waves 0-3) ================
    Frag obf[4];                           // waves 0-3: out_w B-frags (live P4->P5)
    if (wv >= 8) {
        const int w2 = wv - 8;
        const int f = w2 * 16 + arow;
        float bir = b_ih[f], biz = b_ih[128 + f], bin = b_ih[256 + f];
        float bhr = b_hh[f], bhz = b_hh[128 + f], bhn = b_hh[256 + f];
        Frag xA[4];
        #pragma unroll
        for (int kf = 0; kf < 4; ++kf)
            *(uint4*)xA[kf].u = *(const uint4*)&xb16[arow][kf * 32 + kgrp];
        f32x4 gi0 = {0.f, 0.f, 0.f, 0.f}, gi1 = gi0, gi2 = gi0;
        #pragma unroll
        for (int kf = 0; kf < 4; ++kf) {
            gi0 = MFMA16(xA[kf].v, bfr[kf].v, gi0);
            gi1 = MFMA16(xA[kf].v, bfr[4 + kf].v, gi1);
            gi2 = MFMA16(xA[kf].v, bfr[8 + kf].v, gi2);
        }
        if (lane < 32) {
            #pragma unroll
            for (int j = 0; j < 4; ++j) {
                int row = hi * 4 + j;
                float rg = sigm(gi0[j] + bir + gh0[j] + bhr);
                float zg = sigm(gi1[j] + biz + gh1[j] + bhz);
                float ng = tanh_fast(gi2[j] + bin + rg * (gh2[j] + bhn));
                float hprev = hf32[row * 128 + f];
                float hnew = (1.0f - zg) * ng + zg * hprev;
                hnb16[row][f] = cvt1(hnew);
                out[kOut0 + ((size_t)(b * kN + row0 + row)) * kH + f] = hnew;
            }
        }
    } else if (wv < 4) {
        const uint4* wsf = ws + ((size_t)(FW_OUTW + wv * 4) * 64 + lane);
        #pragma unroll
        for (int kf = 0; kf < 4; ++kf)
            *(uint4*)obf[kf].u = wsf[(size_t)kf * 64];
    }
    __syncthreads();

    // ================ P5: out head (waves 0-3) ================
    if (wv < 4) {
        f32x4 acc = {0.f, 0.f, 0.f, 0.f};
        #pragma unroll
        for (int kf = 0; kf < 4; ++kf) {
            Frag a;
            *(uint4*)a.u = *(const uint4*)&hnb16[arow][kf * 32 + kgrp];
            acc = MFMA16(a.v, obf[kf].v, acc);
        }
        if (lane < 32) {
            const int n0 = 16 * wv;
            float ob = out_b[n0 + arow];
            #pragma unroll
            for (int j = 0; j < 4; ++j) {
                int row = hi * 4 + j;
                out[((size_t)(b * kN + row0 + row)) * kO + n0 + arow] = acc[j] + ob;
            }
        }
    }
}

} // namespace

extern "C" void kernel_launch(void* const* d_in, const int* in_sizes, int n_in,
                              void* d_out, int out_size, void* d_ws, size_t ws_size,
                              hipStream_t stream) {
    const float* lx      = (const float*)d_in[0];
    const float* gx      = (const float*)d_in[1];
    const float* mask    = (const float*)d_in[2];
    const int*   key_idx = (const int*)  d_in[3];
    const float* hs      = (const float*)d_in[4];
    const float* fc_w    = (const float*)d_in[5];
    const float* fc_b    = (const float*)d_in[6];
    const float* ln_g    = (const float*)d_in[7];
    const float* ln_b    = (const float*)d_in[8];
    const float* w_ih    = (const float*)d_in[9];
    const float* w_hh    = (const float*)d_in[10];
    const float* b_ih    = (const float*)d_in[11];
    const float* b_hh    = (const float*)d_in[12];
    const float* out_w   = (const float*)d_in[13];
    const float* out_b   = (const float*)d_in[14];
    float* out = (float*)d_out;
    uint4* ws = (uint4*)d_ws;   // needs 816 KB

    hipLaunchKernelGGL(convert_frags, dim3((FW_TOTAL * 64) / 256), dim3(256), 0, stream,
                       gx, fc_w, w_ih, w_hh, out_w, ws);

    dim3 grid(kB * kN / kR);   // 256 blocks
    dim3 block(kTPB);          // 1024 threads = 16 waves
    hipLaunchKernelGGL(weak_tie_fused, grid, block, 0, stream,
                       lx, gx, mask, key_idx, hs,
                       fc_b, ln_g, ln_b,
                       b_ih, b_hh, out_b,
                       (const uint4*)ws, out);
}